// Round 4
// baseline (567.890 us; speedup 1.0000x reference)
//
#include <hip/hip_runtime.h>
#include <hip/hip_bf16.h>

// ---------- types ----------
typedef __bf16 bf16x8 __attribute__((ext_vector_type(8)));
typedef float  f32x4  __attribute__((ext_vector_type(4)));
typedef unsigned short u16;

__device__ __forceinline__ u16 f2bf(float f) {
    __hip_bfloat16 h = __float2bfloat16(f);   // RNE
    return __builtin_bit_cast(unsigned short, h);
}
__device__ __forceinline__ float bf2f(u16 u) {
    return __bfloat162float(__builtin_bit_cast(__hip_bfloat16, u));
}
// fast tanh: 1 - 2/(exp(2x)+1); exact at +/-inf, ~1e-6 abs err (ok vs bf16 noise)
__device__ __forceinline__ float fast_tanh(float x) {
    float e = __expf(2.f * x);
    return 1.f - 2.f / (e + 1.f);
}

// mode: 0=sum, 1=max, 2=min   (256-thread blocks = 4 waves)
template <int MODE>
__device__ __forceinline__ float blockReduce(float v, float* sbuf) {
    #pragma unroll
    for (int off = 32; off > 0; off >>= 1) {
        float o = __shfl_down(v, off, 64);
        v = (MODE == 0) ? v + o : (MODE == 1) ? fmaxf(v, o) : fminf(v, o);
    }
    int lane = threadIdx.x & 63, w = threadIdx.x >> 6;
    __syncthreads();                 // protect sbuf from previous use
    if (lane == 0) sbuf[w] = v;
    __syncthreads();
    float r = sbuf[0];
    #pragma unroll
    for (int i = 1; i < 4; ++i) {
        float o = sbuf[i];
        r = (MODE == 0) ? r + o : (MODE == 1) ? fmaxf(r, o) : fminf(r, o);
    }
    return r;
}

// ---------- prep: x fp32 -> xh bf16 + xsq + fp32 passthrough to out_x ----------
// also zero-inits scaleAcc[r] (per-row fused^2 accumulator used by GEMM-B/C)
__global__ void convert_x(const float* __restrict__ src, u16* __restrict__ dst,
                          float* __restrict__ rowsq, float* __restrict__ copyOut,
                          float* __restrict__ scaleAcc) {
    __shared__ float sbuf[4];
    int r = blockIdx.x, t = threadIdx.x;
    size_t base = (size_t)r * 2048 + t * 8;
    float4 a0 = *(const float4*)(src + base);
    float4 a1 = *(const float4*)(src + base + 4);
    float ss = a0.x*a0.x + a0.y*a0.y + a0.z*a0.z + a0.w*a0.w
             + a1.x*a1.x + a1.y*a1.y + a1.z*a1.z + a1.w*a1.w;
    ushort4 u0, u1;
    u0.x = f2bf(a0.x); u0.y = f2bf(a0.y); u0.z = f2bf(a0.z); u0.w = f2bf(a0.w);
    u1.x = f2bf(a1.x); u1.y = f2bf(a1.y); u1.z = f2bf(a1.z); u1.w = f2bf(a1.w);
    *(ushort4*)(dst + base)     = u0;
    *(ushort4*)(dst + base + 4) = u1;
    *(float4*)(copyOut + base)     = a0;
    *(float4*)(copyOut + base + 4) = a1;
    ss = blockReduce<0>(ss, sbuf);
    if (t == 0) {
        rowsq[r] = ss;
        scaleAcc[r] = 0.f;   // re-zeroed every graph replay, before GEMM-B
    }
}

// ---------- prep: merged weight convert -> Bp [4096,2048] bf16 (+ W_cos normalize) ----------
// blocks 0..1023 = cent (valid<1000, csq), 1024..2047 = W_hall (valid<1000),
// 2048..4095 = W_sel, 4096..5119 = W_cos row-normalize -> ew (zero-pad rows >=1000)
__global__ void convert_weights(const float* __restrict__ cent, const float* __restrict__ whall,
                                const float* __restrict__ wsel, u16* __restrict__ Bp,
                                float* __restrict__ csq,
                                const float* __restrict__ wcos, u16* __restrict__ ew) {
    __shared__ float sbuf[4];
    int r = blockIdx.x, t = threadIdx.x;
    if (r >= 4096) {
        // --- norm_rows path: W_cos row r' -> ew, row-normalized bf16 ---
        int rr = r - 4096;
        size_t base = (size_t)rr * 2048 + t * 8;
        ushort4 u0 = {0,0,0,0}, u1 = {0,0,0,0};
        if (rr < 1000) {
            float4 a0 = *(const float4*)(wcos + base);
            float4 a1 = *(const float4*)(wcos + base + 4);
            float ss = a0.x*a0.x + a0.y*a0.y + a0.z*a0.z + a0.w*a0.w
                     + a1.x*a1.x + a1.y*a1.y + a1.z*a1.z + a1.w*a1.w;
            ss = blockReduce<0>(ss, sbuf);
            float sc = 1.f / sqrtf(ss);
            u0.x = f2bf(a0.x*sc); u0.y = f2bf(a0.y*sc); u0.z = f2bf(a0.z*sc); u0.w = f2bf(a0.w*sc);
            u1.x = f2bf(a1.x*sc); u1.y = f2bf(a1.y*sc); u1.z = f2bf(a1.z*sc); u1.w = f2bf(a1.w*sc);
        }
        *(ushort4*)(ew + base)     = u0;
        *(ushort4*)(ew + base + 4) = u1;
        return;
    }
    const float* src; int sr; bool valid;
    if (r < 1024)       { src = cent;  sr = r;        valid = sr < 1000; }
    else if (r < 2048)  { src = whall; sr = r - 1024; valid = sr < 1000; }
    else                { src = wsel;  sr = r - 2048; valid = true; }
    size_t dbase = (size_t)r * 2048 + t * 8;
    float ss = 0.f;
    ushort4 u0 = {0,0,0,0}, u1 = {0,0,0,0};
    if (valid) {
        size_t sbase = (size_t)sr * 2048 + t * 8;
        float4 a0 = *(const float4*)(src + sbase);
        float4 a1 = *(const float4*)(src + sbase + 4);
        ss = a0.x*a0.x + a0.y*a0.y + a0.z*a0.z + a0.w*a0.w
           + a1.x*a1.x + a1.y*a1.y + a1.z*a1.z + a1.w*a1.w;
        u0.x = f2bf(a0.x); u0.y = f2bf(a0.y); u0.z = f2bf(a0.z); u0.w = f2bf(a0.w);
        u1.x = f2bf(a1.x); u1.y = f2bf(a1.y); u1.z = f2bf(a1.z); u1.w = f2bf(a1.w);
    }
    *(ushort4*)(Bp + dbase)     = u0;
    *(ushort4*)(Bp + dbase + 4) = u1;
    if (r < 1024) {
        ss = blockReduce<0>(ss, sbuf);
        if (t == 0) csq[r] = ss;
    }
}

// ---------- prep: centroids [1000,2048] fp32 -> centT [2048,1024] bf16 (transposed, K-padded) ----------
__global__ void transpose_to_bf16(const float* __restrict__ src, u16* __restrict__ dst, int validRows) {
    __shared__ u16 tile[32][33];
    int d0 = blockIdx.x * 32;   // feature base (src col)
    int c0 = blockIdx.y * 32;   // class base  (src row)
    int tx = threadIdx.x, ty = threadIdx.y;
    #pragma unroll
    for (int k = 0; k < 4; ++k) {
        int c = c0 + ty + k * 8;
        float v = (c < validRows) ? src[(size_t)c * 2048 + d0 + tx] : 0.f;
        tile[ty + k * 8][tx] = f2bf(v);
    }
    __syncthreads();
    #pragma unroll
    for (int k = 0; k < 4; ++k) {
        int d = d0 + ty + k * 8;
        dst[(size_t)d * 1024 + c0 + tx] = tile[tx][ty + k * 8];
    }
}

// ---------- GEMM: C[M,N] = A[M,K(lda)]bf16 @ Bt[N,K(lda)]bf16^T, fp32 accum ----------
// 128x128 tile, BK=64, 256 threads (4 waves 2x2), each wave 64x64 via 4x4 of 16x16x32 MFMA.
// LDS XOR-swizzled (16B granule g of row r holds logical granule g^(r&7)): conflict-free
// while keeping global_load_lds staging segments identical.
// K = extent of this block's K-slice; lda = row stride; blockIdx.z picks the
// K-slice (split-K). For split-K the epilogue must be linear in acc (EPI 3).
// NOTE: default linear block order is already XCD-optimal for these grids
// (XCD = bx%8 keeps B-col-panels L2-resident per XCD; A streams via L3
// temporally aligned across XCDs). Measured: remapping regressed (R2: FETCH
// 161MB -> 410MB). Do not swizzle blockIdx here.
// EPI 1: bf16 store to Cb
// EPI 2: acc = memf; inf = tanh(sel[r,c]+bias[c])*acc -> Cf (fp32);
//        fused = reach[r]*(xh[r,c]+inf) -> fusedh (bf16);
//        scaleAcc[row] += sum(fused^2)  (shfl-reduced, 1 atomic per row-quad)
// EPI 3: Cf[r,c] += (16/(1+sqrt(bias[r]))) * acc  (atomic; col < nValid; Cf pre-zeroed)
template <int EPI>
__global__ __launch_bounds__(256, 4)
void gemm_bt(const u16* __restrict__ A, const u16* __restrict__ Bt,
             float* __restrict__ Cf, u16* __restrict__ Cb,
             int K, int lda, int ldc, int nValid,
             const float* __restrict__ bias,
             const u16* __restrict__ selp, int ldsel,
             const float* __restrict__ reach, const u16* __restrict__ xh2,
             u16* __restrict__ fusedh, float* __restrict__ scaleAcc) {
    __shared__ u16 As[128 * 64];
    __shared__ u16 Bs[128 * 64];
    const int tid  = threadIdx.x;
    const int lane = tid & 63;
    const int w    = tid >> 6;
    const int wr   = w >> 1, wc = w & 1;
    const int quad = lane >> 4, r16 = lane & 15;
    const int sw   = r16 & 7;            // reader swizzle key
    const int lr   = lane >> 3;          // staging: row within 8-row chunk (0..7)
    const int lc   = lane & 7;           // staging: physical granule slot (0..7)
    const int lk   = (lc ^ lr) * 8;      // staging: swizzled logical k elem offset
    const size_t rowBase = (size_t)blockIdx.y * 128;
    const size_t colBase = (size_t)blockIdx.x * 128;
    const int kOff = blockIdx.z * K;     // split-K slice base

    f32x4 acc[4][4] = {};

    for (int kt = 0; kt < K; kt += 64) {
        #pragma unroll
        for (int i = 0; i < 4; ++i) {
            int ci = w * 4 + i;   // chunk 0..15, 8 rows each
            const u16* ga = A  + (rowBase + ci * 8 + lr) * (size_t)lda + kOff + kt + lk;
            const u16* gb = Bt + (colBase + ci * 8 + lr) * (size_t)lda + kOff + kt + lk;
            __builtin_amdgcn_global_load_lds(
                (const __attribute__((address_space(1))) void*)ga,
                (__attribute__((address_space(3))) void*)(As + ci * 512), 16, 0, 0);
            __builtin_amdgcn_global_load_lds(
                (const __attribute__((address_space(1))) void*)gb,
                (__attribute__((address_space(3))) void*)(Bs + ci * 512), 16, 0, 0);
        }
        __syncthreads();
        #pragma unroll
        for (int kk2 = 0; kk2 < 2; ++kk2) {
            // logical granule = kk2*4 + quad; physical = logical ^ sw
            const int off = (((kk2 << 2) | quad) ^ sw) * 8;
            bf16x8 a[4], b[4];
            #pragma unroll
            for (int i = 0; i < 4; ++i)
                a[i] = *(const bf16x8*)(As + (wr * 64 + i * 16 + r16) * 64 + off);
            #pragma unroll
            for (int j = 0; j < 4; ++j)
                b[j] = *(const bf16x8*)(Bs + (wc * 64 + j * 16 + r16) * 64 + off);
            #pragma unroll
            for (int i = 0; i < 4; ++i)
                #pragma unroll
                for (int j = 0; j < 4; ++j)
                    acc[i][j] = __builtin_amdgcn_mfma_f32_16x16x32_bf16(a[i], b[j], acc[i][j], 0, 0, 0);
        }
        __syncthreads();
    }

    // epilogue: C/D layout col=lane&15, row=quad*4+reg (verified m89/m91)
    if (EPI == 2) {
        #pragma unroll
        for (int i = 0; i < 4; ++i) {
            #pragma unroll
            for (int v = 0; v < 4; ++v) {
                size_t grow = rowBase + wr * 64 + i * 16 + quad * 4 + v;
                float rch = reach[grow];
                float rs = 0.f;
                #pragma unroll
                for (int j = 0; j < 4; ++j) {
                    size_t gcol = colBase + wc * 64 + j * 16 + r16;
                    float val = acc[i][j][v];
                    float sv  = bf2f(selp[grow * (size_t)ldsel + gcol]);
                    float t   = fast_tanh(sv + bias[gcol]);
                    float inf = t * val;
                    Cf[grow * (size_t)ldc + gcol] = inf;
                    float xv = bf2f(xh2[grow * (size_t)ldc + gcol]);
                    float fs = rch * (xv + inf);
                    fusedh[grow * (size_t)ldc + gcol] = f2bf(fs);
                    rs += fs * fs;
                }
                // lanes of one quad (r16=0..15) share this row; reduce & one atomic
                #pragma unroll
                for (int off = 8; off > 0; off >>= 1)
                    rs += __shfl_down(rs, off, 16);
                if (r16 == 0) atomicAdd(&scaleAcc[grow], rs);
            }
        }
    } else {
        #pragma unroll
        for (int i = 0; i < 4; ++i) {
            #pragma unroll
            for (int j = 0; j < 4; ++j) {
                #pragma unroll
                for (int v = 0; v < 4; ++v) {
                    size_t grow = rowBase + wr * 64 + i * 16 + quad * 4 + v;
                    size_t gcol = colBase + wc * 64 + j * 16 + r16;
                    float val = acc[i][j][v];
                    if (EPI == 1) {
                        Cb[grow * (size_t)ldc + gcol] = f2bf(val);
                    } else if (EPI == 3) {
                        if ((int)gcol < nValid) {
                            float sc = 16.f / (1.f + sqrtf(bias[grow]));
                            atomicAdd(&Cf[grow * (size_t)ldc + gcol], sc * val);
                        }
                    }
                }
            }
        }
    }
}

// ---------- merged: min distance -> reachability, softmax -> Vm ----------
// Sp is [B,4096] bf16: cols 0..999 = x.cent, 1024..2023 = x.W_hall (2048..4095 = sel, unused here)
// vectorized: thread t handles classes 4t..4t+3 (t<250); t in [250,256) zero-pads Vm.
// Also zero-inits out_logits row r (GEMM-C split-K accumulates atomically into it).
__global__ void min_softmax(const u16* __restrict__ Sp, const float* __restrict__ xsq,
                            const float* __restrict__ csq, const float* __restrict__ bh,
                            float* __restrict__ reach, u16* __restrict__ Vm,
                            float* __restrict__ outLog) {
    __shared__ float sbuf[4];
    int r = blockIdx.x, t = threadIdx.x;
    size_t rb = (size_t)r * 4096;
    int c0 = t * 4;
    // --- zero out_logits row (1000 fp32; row base r*4000B is 16B-aligned) ---
    if (t < 250) {
        float4 z = {0.f, 0.f, 0.f, 0.f};
        *(float4*)(outLog + (size_t)r * 1000 + c0) = z;
    }
    // --- min distance ---
    float m = 1e30f;
    if (t < 250) {
        ushort4 d4 = *(const ushort4*)(Sp + rb + c0);
        float4 cq = *(const float4*)(csq + c0);
        m = fminf(fminf(cq.x - 2.f * bf2f(d4.x), cq.y - 2.f * bf2f(d4.y)),
                  fminf(cq.z - 2.f * bf2f(d4.z), cq.w - 2.f * bf2f(d4.w)));
    }
    m = blockReduce<2>(m, sbuf);
    if (t == 0) {
        float d2 = xsq[r] + m;
        reach[r] = 10.f / sqrtf(fmaxf(d2, 0.f));
    }
    // --- softmax over 1000 classes ---
    float l[4];
    float mx = -1e30f;
    if (t < 250) {
        ushort4 h4 = *(const ushort4*)(Sp + rb + 1024 + c0);
        float4 b4 = *(const float4*)(bh + c0);
        l[0] = bf2f(h4.x) + b4.x;
        l[1] = bf2f(h4.y) + b4.y;
        l[2] = bf2f(h4.z) + b4.z;
        l[3] = bf2f(h4.w) + b4.w;
        mx = fmaxf(fmaxf(l[0], l[1]), fmaxf(l[2], l[3]));
    } else {
        l[0] = l[1] = l[2] = l[3] = -1e30f;
    }
    mx = blockReduce<1>(mx, sbuf);
    float s = 0.f;
    #pragma unroll
    for (int i = 0; i < 4; ++i) {
        l[i] = (t < 250) ? __expf(l[i] - mx) : 0.f;
        s += l[i];
    }
    s = blockReduce<0>(s, sbuf);
    float inv = 1.f / s;
    ushort4 o;
    o.x = f2bf(l[0] * inv); o.y = f2bf(l[1] * inv);
    o.z = f2bf(l[2] * inv); o.w = f2bf(l[3] * inv);
    *(ushort4*)(Vm + (size_t)r * 1024 + c0) = o;   // t>=250 stores zeros (pads 1000..1023)
}

extern "C" void kernel_launch(void* const* d_in, const int* in_sizes, int n_in,
                              void* d_out, int out_size, void* d_ws, size_t ws_size,
                              hipStream_t stream) {
    const float* x      = (const float*)d_in[0];   // [8192,2048]
    const float* cent   = (const float*)d_in[1];   // [1000,2048]
    const float* W_hall = (const float*)d_in[2];   // [1000,2048]
    const float* b_hall = (const float*)d_in[3];   // [1000]
    const float* W_sel  = (const float*)d_in[4];   // [2048,2048]
    const float* b_sel  = (const float*)d_in[5];   // [2048]
    const float* W_cos  = (const float*)d_in[6];   // [1000,2048]

    float* out_logits = (float*)d_out;                          // [8192,1000]
    float* out_x      = out_logits + (size_t)8192 * 1000;       // [8192,2048]
    float* out_inf    = out_x      + (size_t)8192 * 2048;       // [8192,2048]

    char* ws = (char*)d_ws;
    u16*   xh     = (u16*)  (ws);                  // 33554432 B  [8192,2048] bf16
    u16*   Bp     = (u16*)  (ws + 33554432);       // 16777216 B  [4096,2048] bf16: cent|W_hall|W_sel
    u16*   ew     = (u16*)  (ws + 50331648);       //  4194304 B  [1024,2048]
    u16*   centT  = (u16*)  (ws + 54525952);       //  4194304 B  [2048,1024]
    u16*   Sp     = (u16*)  (ws + 58720256);       // 67108864 B  [8192,4096] bf16 (dot|H|sel)
    u16*   Vm     = (u16*)  (ws + 125829120);      // 16777216 B  [8192,1024] bf16
    u16*   fusedh = (u16*)  (ws + 142606336);      // 33554432 B  [8192,2048] bf16
    float* xsq    = (float*)(ws + 176160768);      //    32768 B
    float* csq    = (float*)(ws + 176193536);      //     4096 B
    float* reach  = (float*)(ws + 176197632);      //    32768 B
    float* scale  = (float*)(ws + 176230400);      //    32768 B  (raw sum(fused^2) per row)

    (void)in_sizes; (void)n_in; (void)out_size; (void)ws_size;

    // prep (convert_x also streams the fp32 passthrough to out_x and zeroes scale)
    convert_x<<<8192, 256, 0, stream>>>(x, xh, xsq, out_x, scale);
    convert_weights<<<5120, 256, 0, stream>>>(cent, W_hall, W_sel, Bp, csq, W_cos, ew);
    transpose_to_bf16<<<dim3(64, 32), dim3(32, 8), 0, stream>>>(cent, centT, 1000);

    // GEMM-A: Sp = x @ [cent | W_hall | W_sel]^T  (N=4096, bf16 out)
    gemm_bt<1><<<dim3(32, 64), 256, 0, stream>>>(xh, Bp, nullptr, Sp, 2048, 2048, 4096, 0,
                                                 nullptr, nullptr, 0, nullptr, nullptr, nullptr, nullptr);
    // min/reach + softmax (also zero-inits out_logits for GEMM-C's atomic accum)
    min_softmax<<<8192, 256, 0, stream>>>(Sp, xsq, csq, b_hall, reach, Vm, out_logits);

    // GEMM-B: acc = Vm @ cent (memf); epilogue: inf=tanh(sel+b_sel)*acc -> out_inf,
    //         fused=reach*(x+inf) -> fusedh, scale[row] += sum(fused^2)
    gemm_bt<2><<<dim3(16, 64), 256, 0, stream>>>(Vm, centT, out_inf, nullptr, 1024, 1024, 2048, 0,
                                                 b_sel, Sp + 2048, 4096, reach, xh, fusedh, scale);

    // GEMM-C: logits += (16/(1+sqrt(scale[row]))) * (fused @ ew^T), split-K=2
    // (1024 blocks -> 4/CU occupancy vs 512 -> 2/CU; epilogue linear in acc)
    gemm_bt<3><<<dim3(8, 64, 2), 256, 0, stream>>>(fusedh, ew, out_logits, nullptr, 1024, 2048, 1000, 1000,
                                                   scale, nullptr, 0, nullptr, nullptr, nullptr, nullptr);
}

// Round 5
// 504.672 us; speedup vs baseline: 1.1253x; 1.1253x over previous
//
#include <hip/hip_runtime.h>
#include <hip/hip_bf16.h>

// ---------- types ----------
typedef __bf16 bf16x8 __attribute__((ext_vector_type(8)));
typedef float  f32x4  __attribute__((ext_vector_type(4)));
typedef unsigned short u16;

__device__ __forceinline__ u16 f2bf(float f) {
    __hip_bfloat16 h = __float2bfloat16(f);   // RNE
    return __builtin_bit_cast(unsigned short, h);
}
__device__ __forceinline__ float bf2f(u16 u) {
    return __bfloat162float(__builtin_bit_cast(__hip_bfloat16, u));
}
// fast tanh: 1 - 2/(exp(2x)+1); exact at +/-inf, ~1e-6 abs err (ok vs bf16 noise)
__device__ __forceinline__ float fast_tanh(float x) {
    float e = __expf(2.f * x);
    return 1.f - 2.f / (e + 1.f);
}

// mode: 0=sum, 1=max, 2=min   (256-thread blocks = 4 waves)
template <int MODE>
__device__ __forceinline__ float blockReduce(float v, float* sbuf) {
    #pragma unroll
    for (int off = 32; off > 0; off >>= 1) {
        float o = __shfl_down(v, off, 64);
        v = (MODE == 0) ? v + o : (MODE == 1) ? fmaxf(v, o) : fminf(v, o);
    }
    int lane = threadIdx.x & 63, w = threadIdx.x >> 6;
    __syncthreads();                 // protect sbuf from previous use
    if (lane == 0) sbuf[w] = v;
    __syncthreads();
    float r = sbuf[0];
    #pragma unroll
    for (int i = 1; i < 4; ++i) {
        float o = sbuf[i];
        r = (MODE == 0) ? r + o : (MODE == 1) ? fmaxf(r, o) : fminf(r, o);
    }
    return r;
}

// ---------- prep: x fp32 -> xh bf16 + xsq + fp32 passthrough to out_x ----------
// also zero-inits scaleAcc[r] (per-row fused^2 accumulator used by GEMM-B/C)
__global__ void convert_x(const float* __restrict__ src, u16* __restrict__ dst,
                          float* __restrict__ rowsq, float* __restrict__ copyOut,
                          float* __restrict__ scaleAcc) {
    __shared__ float sbuf[4];
    int r = blockIdx.x, t = threadIdx.x;
    size_t base = (size_t)r * 2048 + t * 8;
    float4 a0 = *(const float4*)(src + base);
    float4 a1 = *(const float4*)(src + base + 4);
    float ss = a0.x*a0.x + a0.y*a0.y + a0.z*a0.z + a0.w*a0.w
             + a1.x*a1.x + a1.y*a1.y + a1.z*a1.z + a1.w*a1.w;
    ushort4 u0, u1;
    u0.x = f2bf(a0.x); u0.y = f2bf(a0.y); u0.z = f2bf(a0.z); u0.w = f2bf(a0.w);
    u1.x = f2bf(a1.x); u1.y = f2bf(a1.y); u1.z = f2bf(a1.z); u1.w = f2bf(a1.w);
    *(ushort4*)(dst + base)     = u0;
    *(ushort4*)(dst + base + 4) = u1;
    *(float4*)(copyOut + base)     = a0;
    *(float4*)(copyOut + base + 4) = a1;
    ss = blockReduce<0>(ss, sbuf);
    if (t == 0) {
        rowsq[r] = ss;
        scaleAcc[r] = 0.f;   // re-zeroed every graph replay, before GEMM-B
    }
}

// ---------- prep: merged weight convert -> Bp [4096,2048] bf16 (+ W_cos normalize) ----------
// blocks 0..1023 = cent (valid<1000, csq), 1024..2047 = W_hall (valid<1000),
// 2048..4095 = W_sel, 4096..5119 = W_cos row-normalize -> ew (zero-pad rows >=1000)
__global__ void convert_weights(const float* __restrict__ cent, const float* __restrict__ whall,
                                const float* __restrict__ wsel, u16* __restrict__ Bp,
                                float* __restrict__ csq,
                                const float* __restrict__ wcos, u16* __restrict__ ew) {
    __shared__ float sbuf[4];
    int r = blockIdx.x, t = threadIdx.x;
    if (r >= 4096) {
        // --- norm_rows path: W_cos row r' -> ew, row-normalized bf16 ---
        int rr = r - 4096;
        size_t base = (size_t)rr * 2048 + t * 8;
        ushort4 u0 = {0,0,0,0}, u1 = {0,0,0,0};
        if (rr < 1000) {
            float4 a0 = *(const float4*)(wcos + base);
            float4 a1 = *(const float4*)(wcos + base + 4);
            float ss = a0.x*a0.x + a0.y*a0.y + a0.z*a0.z + a0.w*a0.w
                     + a1.x*a1.x + a1.y*a1.y + a1.z*a1.z + a1.w*a1.w;
            ss = blockReduce<0>(ss, sbuf);
            float sc = 1.f / sqrtf(ss);
            u0.x = f2bf(a0.x*sc); u0.y = f2bf(a0.y*sc); u0.z = f2bf(a0.z*sc); u0.w = f2bf(a0.w*sc);
            u1.x = f2bf(a1.x*sc); u1.y = f2bf(a1.y*sc); u1.z = f2bf(a1.z*sc); u1.w = f2bf(a1.w*sc);
        }
        *(ushort4*)(ew + base)     = u0;
        *(ushort4*)(ew + base + 4) = u1;
        return;
    }
    const float* src; int sr; bool valid;
    if (r < 1024)       { src = cent;  sr = r;        valid = sr < 1000; }
    else if (r < 2048)  { src = whall; sr = r - 1024; valid = sr < 1000; }
    else                { src = wsel;  sr = r - 2048; valid = true; }
    size_t dbase = (size_t)r * 2048 + t * 8;
    float ss = 0.f;
    ushort4 u0 = {0,0,0,0}, u1 = {0,0,0,0};
    if (valid) {
        size_t sbase = (size_t)sr * 2048 + t * 8;
        float4 a0 = *(const float4*)(src + sbase);
        float4 a1 = *(const float4*)(src + sbase + 4);
        ss = a0.x*a0.x + a0.y*a0.y + a0.z*a0.z + a0.w*a0.w
           + a1.x*a1.x + a1.y*a1.y + a1.z*a1.z + a1.w*a1.w;
        u0.x = f2bf(a0.x); u0.y = f2bf(a0.y); u0.z = f2bf(a0.z); u0.w = f2bf(a0.w);
        u1.x = f2bf(a1.x); u1.y = f2bf(a1.y); u1.z = f2bf(a1.z); u1.w = f2bf(a1.w);
    }
    *(ushort4*)(Bp + dbase)     = u0;
    *(ushort4*)(Bp + dbase + 4) = u1;
    if (r < 1024) {
        ss = blockReduce<0>(ss, sbuf);
        if (t == 0) csq[r] = ss;
    }
}

// ---------- prep: centroids [1000,2048] fp32 -> centT [2048,1024] bf16 (transposed, K-padded) ----------
__global__ void transpose_to_bf16(const float* __restrict__ src, u16* __restrict__ dst, int validRows) {
    __shared__ u16 tile[32][33];
    int d0 = blockIdx.x * 32;   // feature base (src col)
    int c0 = blockIdx.y * 32;   // class base  (src row)
    int tx = threadIdx.x, ty = threadIdx.y;
    #pragma unroll
    for (int k = 0; k < 4; ++k) {
        int c = c0 + ty + k * 8;
        float v = (c < validRows) ? src[(size_t)c * 2048 + d0 + tx] : 0.f;
        tile[ty + k * 8][tx] = f2bf(v);
    }
    __syncthreads();
    #pragma unroll
    for (int k = 0; k < 4; ++k) {
        int d = d0 + ty + k * 8;
        dst[(size_t)d * 1024 + c0 + tx] = tile[tx][ty + k * 8];
    }
}

// ---------- GEMM: C[M,N] = A[M,K]bf16 @ Bt[N,K]bf16^T, fp32 accum ----------
// 128x128 tile, BK=64, 256 threads (4 waves 2x2), each wave 64x64 via 4x4 of 16x16x32 MFMA.
// LDS XOR-swizzled (16B granule g of row r holds logical granule g^(r&7)): conflict-free
// while keeping global_load_lds staging segments identical.
// NOTE: default linear block order is already XCD-optimal for these grids
// (XCD = bx%8 keeps B-col-panels L2-resident per XCD). Measured: remapping
// regressed (R2: FETCH 161->410MB). Split-K via output atomics also regressed
// (R4: +51us, 16M fp32 RMW). Keep plain stores, default order.
// EPI 1: bf16 store to Cb
// EPI 2: acc = memf; inf = tanh(sel[r,c]+bias[c])*acc -> Cf (fp32);
//        fused = reach[r]*(xh[r,c]+inf) -> fusedh (bf16);
//        scaleAcc[row] += sum(fused^2)  (shfl-reduced, 1 atomic per row-quad)
template <int EPI>
__global__ __launch_bounds__(256, 4)
void gemm_bt(const u16* __restrict__ A, const u16* __restrict__ Bt,
             float* __restrict__ Cf, u16* __restrict__ Cb,
             int K, int ldc,
             const float* __restrict__ bias,
             const u16* __restrict__ selp, int ldsel,
             const float* __restrict__ reach, const u16* __restrict__ xh2,
             u16* __restrict__ fusedh, float* __restrict__ scaleAcc) {
    __shared__ u16 As[128 * 64];
    __shared__ u16 Bs[128 * 64];
    const int tid  = threadIdx.x;
    const int lane = tid & 63;
    const int w    = tid >> 6;
    const int wr   = w >> 1, wc = w & 1;
    const int quad = lane >> 4, r16 = lane & 15;
    const int sw   = r16 & 7;            // reader swizzle key
    const int lr   = lane >> 3;          // staging: row within 8-row chunk (0..7)
    const int lc   = lane & 7;           // staging: physical granule slot (0..7)
    const int lk   = (lc ^ lr) * 8;      // staging: swizzled logical k elem offset
    const size_t rowBase = (size_t)blockIdx.y * 128;
    const size_t colBase = (size_t)blockIdx.x * 128;

    f32x4 acc[4][4] = {};

    for (int kt = 0; kt < K; kt += 64) {
        #pragma unroll
        for (int i = 0; i < 4; ++i) {
            int ci = w * 4 + i;   // chunk 0..15, 8 rows each
            const u16* ga = A  + (rowBase + ci * 8 + lr) * (size_t)K + kt + lk;
            const u16* gb = Bt + (colBase + ci * 8 + lr) * (size_t)K + kt + lk;
            __builtin_amdgcn_global_load_lds(
                (const __attribute__((address_space(1))) void*)ga,
                (__attribute__((address_space(3))) void*)(As + ci * 512), 16, 0, 0);
            __builtin_amdgcn_global_load_lds(
                (const __attribute__((address_space(1))) void*)gb,
                (__attribute__((address_space(3))) void*)(Bs + ci * 512), 16, 0, 0);
        }
        __syncthreads();
        #pragma unroll
        for (int kk2 = 0; kk2 < 2; ++kk2) {
            // logical granule = kk2*4 + quad; physical = logical ^ sw
            const int off = (((kk2 << 2) | quad) ^ sw) * 8;
            bf16x8 a[4], b[4];
            #pragma unroll
            for (int i = 0; i < 4; ++i)
                a[i] = *(const bf16x8*)(As + (wr * 64 + i * 16 + r16) * 64 + off);
            #pragma unroll
            for (int j = 0; j < 4; ++j)
                b[j] = *(const bf16x8*)(Bs + (wc * 64 + j * 16 + r16) * 64 + off);
            #pragma unroll
            for (int i = 0; i < 4; ++i)
                #pragma unroll
                for (int j = 0; j < 4; ++j)
                    acc[i][j] = __builtin_amdgcn_mfma_f32_16x16x32_bf16(a[i], b[j], acc[i][j], 0, 0, 0);
        }
        __syncthreads();
    }

    // epilogue: C/D layout col=lane&15, row=quad*4+reg (verified m89/m91)
    if (EPI == 2) {
        #pragma unroll
        for (int i = 0; i < 4; ++i) {
            #pragma unroll
            for (int v = 0; v < 4; ++v) {
                size_t grow = rowBase + wr * 64 + i * 16 + quad * 4 + v;
                float rch = reach[grow];
                float rs = 0.f;
                #pragma unroll
                for (int j = 0; j < 4; ++j) {
                    size_t gcol = colBase + wc * 64 + j * 16 + r16;
                    float val = acc[i][j][v];
                    float sv  = bf2f(selp[grow * (size_t)ldsel + gcol]);
                    float t   = fast_tanh(sv + bias[gcol]);
                    float inf = t * val;
                    Cf[grow * (size_t)ldc + gcol] = inf;
                    float xv = bf2f(xh2[grow * (size_t)ldc + gcol]);
                    float fs = rch * (xv + inf);
                    fusedh[grow * (size_t)ldc + gcol] = f2bf(fs);
                    rs += fs * fs;
                }
                // lanes of one quad (r16=0..15) share this row; reduce & one atomic
                #pragma unroll
                for (int off = 8; off > 0; off >>= 1)
                    rs += __shfl_down(rs, off, 16);
                if (r16 == 0) atomicAdd(&scaleAcc[grow], rs);
            }
        }
    } else {
        #pragma unroll
        for (int i = 0; i < 4; ++i) {
            #pragma unroll
            for (int j = 0; j < 4; ++j) {
                #pragma unroll
                for (int v = 0; v < 4; ++v) {
                    size_t grow = rowBase + wr * 64 + i * 16 + quad * 4 + v;
                    size_t gcol = colBase + wc * 64 + j * 16 + r16;
                    Cb[grow * (size_t)ldc + gcol] = f2bf(acc[i][j][v]);
                }
            }
        }
    }
}

// ---------- GEMM-C: 64x128 tile (4 blocks/CU), logits = sc[row] * (fused @ ew^T) ----------
// Same 2-phase template & XOR-swizzle invariants as gemm_bt (row&7 == r16&7 holds:
// all row strides are multiples of 8). 4 waves side-by-side in N: wave w owns
// cols w*32..w*32+31 over all 64 rows (acc[4][2]). Grid (8,128) = 1024 blocks
// -> 4/CU (vs 512 -> 2/CU at 128x128), restoring cross-block MFMA/stage overlap.
// LDS 24KB. sc = 16/(1+sqrt(scaleAcc[row])); store only cols < nValid.
__global__ __launch_bounds__(256, 4)
void gemm_c64(const u16* __restrict__ A, const u16* __restrict__ Bt,
              float* __restrict__ Cf, int K, int ldc, int nValid,
              const float* __restrict__ bias) {
    __shared__ u16 As[64 * 64];
    __shared__ u16 Bs[128 * 64];
    const int tid  = threadIdx.x;
    const int lane = tid & 63;
    const int w    = tid >> 6;          // wave 0..3: col group
    const int quad = lane >> 4, r16 = lane & 15;
    const int sw   = r16 & 7;
    const int lr   = lane >> 3;
    const int lc   = lane & 7;
    const int lk   = (lc ^ lr) * 8;
    const size_t rowBase = (size_t)blockIdx.y * 64;
    const size_t colBase = (size_t)blockIdx.x * 128;

    f32x4 acc[4][2] = {};

    for (int kt = 0; kt < K; kt += 64) {
        #pragma unroll
        for (int i = 0; i < 2; ++i) {
            int ci = w * 2 + i;    // A chunks 0..7 (64 rows)
            const u16* ga = A + (rowBase + ci * 8 + lr) * (size_t)K + kt + lk;
            __builtin_amdgcn_global_load_lds(
                (const __attribute__((address_space(1))) void*)ga,
                (__attribute__((address_space(3))) void*)(As + ci * 512), 16, 0, 0);
        }
        #pragma unroll
        for (int i = 0; i < 4; ++i) {
            int ci = w * 4 + i;    // B chunks 0..15 (128 rows)
            const u16* gb = Bt + (colBase + ci * 8 + lr) * (size_t)K + kt + lk;
            __builtin_amdgcn_global_load_lds(
                (const __attribute__((address_space(1))) void*)gb,
                (__attribute__((address_space(3))) void*)(Bs + ci * 512), 16, 0, 0);
        }
        __syncthreads();
        #pragma unroll
        for (int kk2 = 0; kk2 < 2; ++kk2) {
            const int off = (((kk2 << 2) | quad) ^ sw) * 8;
            bf16x8 a[4], b[2];
            #pragma unroll
            for (int i = 0; i < 4; ++i)
                a[i] = *(const bf16x8*)(As + (i * 16 + r16) * 64 + off);
            #pragma unroll
            for (int j = 0; j < 2; ++j)
                b[j] = *(const bf16x8*)(Bs + (w * 32 + j * 16 + r16) * 64 + off);
            #pragma unroll
            for (int i = 0; i < 4; ++i)
                #pragma unroll
                for (int j = 0; j < 2; ++j)
                    acc[i][j] = __builtin_amdgcn_mfma_f32_16x16x32_bf16(a[i], b[j], acc[i][j], 0, 0, 0);
        }
        __syncthreads();
    }

    #pragma unroll
    for (int i = 0; i < 4; ++i) {
        #pragma unroll
        for (int v = 0; v < 4; ++v) {
            size_t grow = rowBase + i * 16 + quad * 4 + v;
            float sc = 16.f / (1.f + sqrtf(bias[grow]));
            #pragma unroll
            for (int j = 0; j < 2; ++j) {
                size_t gcol = colBase + w * 32 + j * 16 + r16;
                if ((int)gcol < nValid)
                    Cf[grow * (size_t)ldc + gcol] = sc * acc[i][j][v];
            }
        }
    }
}

// ---------- merged: min distance -> reachability, softmax -> Vm ----------
// Sp is [B,4096] bf16: cols 0..999 = x.cent, 1024..2023 = x.W_hall (2048..4095 = sel, unused here)
// vectorized: thread t handles classes 4t..4t+3 (t<250); t in [250,256) zero-pads Vm
__global__ void min_softmax(const u16* __restrict__ Sp, const float* __restrict__ xsq,
                            const float* __restrict__ csq, const float* __restrict__ bh,
                            float* __restrict__ reach, u16* __restrict__ Vm) {
    __shared__ float sbuf[4];
    int r = blockIdx.x, t = threadIdx.x;
    size_t rb = (size_t)r * 4096;
    int c0 = t * 4;
    // --- min distance ---
    float m = 1e30f;
    if (t < 250) {
        ushort4 d4 = *(const ushort4*)(Sp + rb + c0);
        float4 cq = *(const float4*)(csq + c0);
        m = fminf(fminf(cq.x - 2.f * bf2f(d4.x), cq.y - 2.f * bf2f(d4.y)),
                  fminf(cq.z - 2.f * bf2f(d4.z), cq.w - 2.f * bf2f(d4.w)));
    }
    m = blockReduce<2>(m, sbuf);
    if (t == 0) {
        float d2 = xsq[r] + m;
        reach[r] = 10.f / sqrtf(fmaxf(d2, 0.f));
    }
    // --- softmax over 1000 classes ---
    float l[4];
    float mx = -1e30f;
    if (t < 250) {
        ushort4 h4 = *(const ushort4*)(Sp + rb + 1024 + c0);
        float4 b4 = *(const float4*)(bh + c0);
        l[0] = bf2f(h4.x) + b4.x;
        l[1] = bf2f(h4.y) + b4.y;
        l[2] = bf2f(h4.z) + b4.z;
        l[3] = bf2f(h4.w) + b4.w;
        mx = fmaxf(fmaxf(l[0], l[1]), fmaxf(l[2], l[3]));
    } else {
        l[0] = l[1] = l[2] = l[3] = -1e30f;
    }
    mx = blockReduce<1>(mx, sbuf);
    float s = 0.f;
    #pragma unroll
    for (int i = 0; i < 4; ++i) {
        l[i] = (t < 250) ? __expf(l[i] - mx) : 0.f;
        s += l[i];
    }
    s = blockReduce<0>(s, sbuf);
    float inv = 1.f / s;
    ushort4 o;
    o.x = f2bf(l[0] * inv); o.y = f2bf(l[1] * inv);
    o.z = f2bf(l[2] * inv); o.w = f2bf(l[3] * inv);
    *(ushort4*)(Vm + (size_t)r * 1024 + c0) = o;   // t>=250 stores zeros (pads 1000..1023)
}

extern "C" void kernel_launch(void* const* d_in, const int* in_sizes, int n_in,
                              void* d_out, int out_size, void* d_ws, size_t ws_size,
                              hipStream_t stream) {
    const float* x      = (const float*)d_in[0];   // [8192,2048]
    const float* cent   = (const float*)d_in[1];   // [1000,2048]
    const float* W_hall = (const float*)d_in[2];   // [1000,2048]
    const float* b_hall = (const float*)d_in[3];   // [1000]
    const float* W_sel  = (const float*)d_in[4];   // [2048,2048]
    const float* b_sel  = (const float*)d_in[5];   // [2048]
    const float* W_cos  = (const float*)d_in[6];   // [1000,2048]

    float* out_logits = (float*)d_out;                          // [8192,1000]
    float* out_x      = out_logits + (size_t)8192 * 1000;       // [8192,2048]
    float* out_inf    = out_x      + (size_t)8192 * 2048;       // [8192,2048]

    char* ws = (char*)d_ws;
    u16*   xh     = (u16*)  (ws);                  // 33554432 B  [8192,2048] bf16
    u16*   Bp     = (u16*)  (ws + 33554432);       // 16777216 B  [4096,2048] bf16: cent|W_hall|W_sel
    u16*   ew     = (u16*)  (ws + 50331648);       //  4194304 B  [1024,2048]
    u16*   centT  = (u16*)  (ws + 54525952);       //  4194304 B  [2048,1024]
    u16*   Sp     = (u16*)  (ws + 58720256);       // 67108864 B  [8192,4096] bf16 (dot|H|sel)
    u16*   Vm     = (u16*)  (ws + 125829120);      // 16777216 B  [8192,1024] bf16
    u16*   fusedh = (u16*)  (ws + 142606336);      // 33554432 B  [8192,2048] bf16
    float* xsq    = (float*)(ws + 176160768);      //    32768 B
    float* csq    = (float*)(ws + 176193536);      //     4096 B
    float* reach  = (float*)(ws + 176197632);      //    32768 B
    float* scale  = (float*)(ws + 176230400);      //    32768 B  (raw sum(fused^2) per row)

    (void)in_sizes; (void)n_in; (void)out_size; (void)ws_size;

    // prep (convert_x also streams the fp32 passthrough to out_x and zeroes scale)
    convert_x<<<8192, 256, 0, stream>>>(x, xh, xsq, out_x, scale);
    convert_weights<<<5120, 256, 0, stream>>>(cent, W_hall, W_sel, Bp, csq, W_cos, ew);
    transpose_to_bf16<<<dim3(64, 32), dim3(32, 8), 0, stream>>>(cent, centT, 1000);

    // GEMM-A: Sp = x @ [cent | W_hall | W_sel]^T  (N=4096, bf16 out)
    gemm_bt<1><<<dim3(32, 64), 256, 0, stream>>>(xh, Bp, nullptr, Sp, 2048, 4096,
                                                 nullptr, nullptr, 0, nullptr, nullptr, nullptr, nullptr);
    min_softmax<<<8192, 256, 0, stream>>>(Sp, xsq, csq, b_hall, reach, Vm);

    // GEMM-B: acc = Vm @ cent (memf); epilogue: inf=tanh(sel+b_sel)*acc -> out_inf,
    //         fused=reach*(x+inf) -> fusedh, scale[row] += sum(fused^2)
    gemm_bt<2><<<dim3(16, 64), 256, 0, stream>>>(Vm, centT, out_inf, nullptr, 1024, 2048,
                                                 b_sel, Sp + 2048, 4096, reach, xh, fusedh, scale);

    // GEMM-C: logits = (16/(1+sqrt(scale[row]))) * (fused @ ew^T)
    // 64x128 tile -> 1024 blocks (4/CU); plain stores (no atomics: R4 lesson)
    gemm_c64<<<dim3(8, 128), 256, 0, stream>>>(fusedh, ew, out_logits, 2048, 1000, 1000, scale);
}